// Round 8
// baseline (105.630 us; speedup 1.0000x reference)
//
#include <hip/hip_runtime.h>
#include <math.h>

// Problem constants (fixed by reference: H=256, N=64, CH=1, L=2048)
#define NH   256
#define NN   64
#define LSEQ 2048
#define SDW  68      // dword row stride: 68 mod 32 = 4 -> b128 phases tile 32 banks x2
#define NTH  512     // 8 waves: 0-3 square (32x32), 4-5 pre-work, 6-7 K-overlap

typedef __attribute__((ext_vector_type(8))) short short8;     // 8 bf16 (MFMA A/B frag)
typedef __attribute__((ext_vector_type(4))) float float4_t;   // MFMA C/D frag

#define MFMA(a,b,c) __builtin_amdgcn_mfma_f32_16x16x32_bf16((a),(b),(c),0,0,0)
#define PERM_HI 0x07060302u   // [a.hi16 | b.hi16]
#define PERM_LO 0x05040100u   // [a.lo16 | b.lo16]

// packed element: dword = [bf16hi | bf16lo], value = hi + lo (16-bit mantissa)
static __device__ __forceinline__ unsigned pack2(float v) {
    unsigned hv = __float_as_uint(v) & 0xffff0000u;
    float lo = v - __uint_as_float(hv);
    return __builtin_amdgcn_perm(hv, __float_as_uint(lo), PERM_HI);
}
static __device__ __forceinline__ float unpack2(unsigned w) {
    return __uint_as_float(w & 0xffff0000u) + __uint_as_float(w << 16);
}

static __device__ __forceinline__ void frag_vals(const unsigned* e, short8& hi, short8& lo) {
    unsigned lb[8];
#pragma unroll
    for (int m = 0; m < 8; ++m) {
        unsigned hv = e[m] & 0xffff0000u;
        lb[m] = __float_as_uint(__uint_as_float(e[m]) - __uint_as_float(hv));
    }
    union { short8 s; unsigned u[4]; } H, L;
#pragma unroll
    for (int m = 0; m < 4; ++m) {
        H.u[m] = __builtin_amdgcn_perm(e[2*m+1],  e[2*m],  PERM_HI);
        L.u[m] = __builtin_amdgcn_perm(lb[2*m+1], lb[2*m], PERM_HI);
    }
    hi = H.s; lo = L.s;
}
static __device__ __forceinline__ void frag_f32(const float* p, short8& hi, short8& lo) {
    const uint4* q = (const uint4*)p;
    uint4 d0 = q[0], d1 = q[1];
    unsigned e[8] = {d0.x, d0.y, d0.z, d0.w, d1.x, d1.y, d1.z, d1.w};
    frag_vals(e, hi, lo);
}
static __device__ __forceinline__ void frag_packed(const unsigned* p, short8& hi, short8& lo) {
    const uint4* q = (const uint4*)p;
    uint4 d0 = q[0], d1 = q[1];
    unsigned e[8] = {d0.x, d0.y, d0.z, d0.w, d1.x, d1.y, d1.z, d1.w};
    union { short8 s; unsigned u[4]; } H, L;
#pragma unroll
    for (int m = 0; m < 4; ++m) {
        H.u[m] = __builtin_amdgcn_perm(e[2*m+1], e[2*m], PERM_HI);
        L.u[m] = __builtin_amdgcn_perm(e[2*m+1], e[2*m], PERM_LO);
    }
    hi = H.s; lo = L.s;
}
static __device__ __forceinline__ short8 neg8(short8 v) {
    union { short8 s; int i[4]; } u; u.s = v;
#pragma unroll
    for (int m = 0; m < 4; ++m) u.i[m] ^= 0x80008000;
    return u.s;
}

// AG x 2 grid of 16x16 complex tiles (AG=1: 16x32 out, AG=2: 32x32), K=64.
// A rows [arow0 ..), B read via its TRANSPOSE array rows [bcol0 ..).
// Negation for Re -= Ai*Bi folded into negated B-imag frags (shared over AG).
template<int AG, bool AP, bool BP, bool IMAG>
static __device__ __forceinline__ void cmm_block(
    const void* Ar_, const void* Ai_, const void* Br_, const void* Bi_,
    int arow0, int bcol0, int fm, int fq,
    float4_t (&accR)[AG][2], float4_t (&accI)[AG][2])
{
#pragma unroll
    for (int ks = 0; ks < 2; ++ks) {
        const int k0 = ks*32 + fq*8;
        short8 Arh[AG], Arl[AG], Aih[AG], Ail[AG];
#pragma unroll
        for (int g = 0; g < AG; ++g) {
            const int row = arow0 + g*16 + fm;
            if (AP) {
                frag_packed((const unsigned*)Ar_ + row*SDW + k0, Arh[g], Arl[g]);
                frag_packed((const unsigned*)Ai_ + row*SDW + k0, Aih[g], Ail[g]);
            } else {
                frag_f32((const float*)Ar_ + row*SDW + k0, Arh[g], Arl[g]);
                frag_f32((const float*)Ai_ + row*SDW + k0, Aih[g], Ail[g]);
            }
        }
#pragma unroll
        for (int bg = 0; bg < 2; ++bg) {
            const int col = bcol0 + bg*16 + fm;
            short8 Brh, Brl, Bih, Bil;
            if (BP) {
                frag_packed((const unsigned*)Br_ + col*SDW + k0, Brh, Brl);
                frag_packed((const unsigned*)Bi_ + col*SDW + k0, Bih, Bil);
            } else {
                frag_f32((const float*)Br_ + col*SDW + k0, Brh, Brl);
                frag_f32((const float*)Bi_ + col*SDW + k0, Bih, Bil);
            }
            short8 nBih = neg8(Bih), nBil = neg8(Bil);
#pragma unroll
            for (int g = 0; g < AG; ++g) {
                accR[g][bg] = MFMA(Arh[g], Brh,  accR[g][bg]);
                accR[g][bg] = MFMA(Arh[g], Brl,  accR[g][bg]);
                accR[g][bg] = MFMA(Arl[g], Brh,  accR[g][bg]);
                accR[g][bg] = MFMA(Aih[g], nBih, accR[g][bg]);
                accR[g][bg] = MFMA(Aih[g], nBil, accR[g][bg]);
                accR[g][bg] = MFMA(Ail[g], nBih, accR[g][bg]);
                if (IMAG) {
                    accI[g][bg] = MFMA(Arh[g], Bih, accI[g][bg]);
                    accI[g][bg] = MFMA(Arh[g], Bil, accI[g][bg]);
                    accI[g][bg] = MFMA(Arl[g], Bih, accI[g][bg]);
                    accI[g][bg] = MFMA(Aih[g], Brh, accI[g][bg]);
                    accI[g][bg] = MFMA(Aih[g], Brl, accI[g][bg]);
                    accI[g][bg] = MFMA(Ail[g], Brh, accI[g][bg]);
                }
            }
        }
    }
}

// k[h, 64j+i] = Re( g_j . x_i ),  g_j = c^T (dA^64)^j,  x_i = dA^i dB
__global__ __launch_bounds__(NTH) void ssm_kernel(
    const float* __restrict__ Ag,
    const float* __restrict__ Bg,
    const float* __restrict__ Cg,
    const float* __restrict__ LogDt,
    float* __restrict__ outp)
{
    __shared__ __align__(16) unsigned char lds[130688];
    unsigned* XRr = (unsigned*)(lds +      0);   // packed P row-major (re)
    unsigned* XRi = (unsigned*)(lds +  17408);   // packed P row-major (im)
    unsigned* XTr = (unsigned*)(lds +  34816);   // packed P^T (re)
    unsigned* XTi = (unsigned*)(lds +  52224);   // packed P^T (im)
    float*    Xfr = (float*)(lds +  69632);      // fp32 Xf[v][q] = x_v[q] ; aliases Newton T^T
    float*    Xfi = (float*)(lds +  87040);
    unsigned* U0u = (unsigned*)Xfr;              // Newton T^T packed (dead before Xf live)
    unsigned* U1u = (unsigned*)Xfi;
    float*    Grf = (float*)(lds + 104448);      // fp32 G[j][q] = g_j[q], 32 rows, stride SDW
    float*    Gif = (float*)(lds + 113152);
    float*    Kof = (float*)(lds + 121856);      // output stage 32 x 65
    float*    bvr = (float*)(lds + 130176);
    float*    bvi = (float*)(lds + 130432);

    const int t    = threadIdx.x;
    const int lane = t & 63;
    const int wv   = t >> 6;                 // 0..7
    const int fm   = lane & 15, fq = lane >> 4;
    const int h    = blockIdx.x;

    const float dt  = expf(LogDt[h]);
    const float hdt = 0.5f * dt;

    const float2* A2 = (const float2*)(Ag + (size_t)h * NN * NN * 2);
    const float4_t z4 = {0.f, 0.f, 0.f, 0.f};

    // ---- seed P = X1 = I + (dt/2)A packed (both views); load b, c ----
#pragma unroll
    for (int e = 0; e < 8; ++e) {
        int idx = t + e*NTH;
        int i = idx >> 6, j = idx & 63;
        float2 a = A2[idx];
        unsigned pr = pack2((i == j ? 1.0f : 0.0f) + hdt * a.x);
        unsigned pi = pack2(hdt * a.y);
        XRr[i*SDW + j] = pr; XRi[i*SDW + j] = pi;
        XTr[j*SDW + i] = pr; XTi[j*SDW + i] = pi;
    }
    if (t < NN) {
        float2 bv = ((const float2*)Bg)[h*NN + t];
        float2 cv = ((const float2*)Cg)[h*NN + t];
        bvr[t] = bv.x; bvi[t] = bv.y;
        Grf[t] = cv.x; Gif[t] = cv.y;   // g_0 = c
    }
    __syncthreads();

    // ---- 2 Newton steps: T = 2I - Ab*X (Ab from global, 8 waves 16x32);
    //      X <- X*T (4 waves 32x32) ----
#pragma unroll 1
    for (int step = 0; step < 2; ++step) {
        {   // m1: wave tile rows [(wv>>1)*16), cols [(wv&1)*32)
            const int arow0 = (wv >> 1) * 16;
            const int bcol0 = (wv & 1) * 32;
            float4_t aR[2], aI[2];
            aR[0] = z4; aR[1] = z4; aI[0] = z4; aI[1] = z4;
#pragma unroll
            for (int ks = 0; ks < 2; ++ks) {
                const int k0 = ks*32 + fq*8;
                const int row = arow0 + fm;
                unsigned vr[8], vi[8];
#pragma unroll
                for (int j = 0; j < 8; ++j) {
                    float2 a = A2[row*NN + k0 + j];
                    vr[j] = __float_as_uint((row == k0 + j ? 1.0f : 0.0f) - hdt * a.x);
                    vi[j] = __float_as_uint(-hdt * a.y);
                }
                short8 Arh, Arl, Aih, Ail;
                frag_vals(vr, Arh, Arl);
                frag_vals(vi, Aih, Ail);
#pragma unroll
                for (int bg = 0; bg < 2; ++bg) {
                    const int col = bcol0 + bg*16 + fm;
                    short8 Brh, Brl, Bih, Bil;
                    frag_packed(XTr + col*SDW + k0, Brh, Brl);
                    frag_packed(XTi + col*SDW + k0, Bih, Bil);
                    short8 nBih = neg8(Bih), nBil = neg8(Bil);
                    aR[bg] = MFMA(Arh, Brh,  aR[bg]); aR[bg] = MFMA(Arh, Brl,  aR[bg]);
                    aR[bg] = MFMA(Arl, Brh,  aR[bg]); aR[bg] = MFMA(Aih, nBih, aR[bg]);
                    aR[bg] = MFMA(Aih, nBil, aR[bg]); aR[bg] = MFMA(Ail, nBih, aR[bg]);
                    aI[bg] = MFMA(Arh, Bih,  aI[bg]); aI[bg] = MFMA(Arh, Bil,  aI[bg]);
                    aI[bg] = MFMA(Arl, Bih,  aI[bg]); aI[bg] = MFMA(Aih, Brh,  aI[bg]);
                    aI[bg] = MFMA(Aih, Brl,  aI[bg]); aI[bg] = MFMA(Ail, Brh,  aI[bg]);
                }
            }
#pragma unroll
            for (int bg = 0; bg < 2; ++bg)
#pragma unroll
                for (int r = 0; r < 4; ++r) {
                    int row = arow0 + fq*4 + r;
                    int col = bcol0 + bg*16 + fm;
                    U0u[col*SDW + row] = pack2((row == col ? 2.0f : 0.0f) - aR[bg][r]);
                    U1u[col*SDW + row] = pack2(-aI[bg][r]);
                }
        }
        __syncthreads();
        // m2: waves 0-3, 32x32
        float4_t bR[2][2], bI[2][2];
        bR[0][0]=z4; bR[0][1]=z4; bR[1][0]=z4; bR[1][1]=z4;
        bI[0][0]=z4; bI[0][1]=z4; bI[1][0]=z4; bI[1][1]=z4;
        if (wv < 4)
            cmm_block<2, true, true, true>(XRr, XRi, U0u, U1u,
                                           (wv>>1)*32, (wv&1)*32, fm, fq, bR, bI);
        __syncthreads();   // all X reads done
        if (wv < 4) {
#pragma unroll
            for (int g = 0; g < 2; ++g)
#pragma unroll
                for (int bg = 0; bg < 2; ++bg)
#pragma unroll
                    for (int r = 0; r < 4; ++r) {
                        int row = (wv>>1)*32 + g*16 + fq*4 + r;
                        int col = (wv&1)*32 + bg*16 + fm;
                        unsigned pr = pack2(bR[g][bg][r]), pi = pack2(bI[g][bg][r]);
                        XRr[row*SDW + col] = pr; XRi[row*SDW + col] = pi;
                        XTr[col*SDW + row] = pr; XTi[col*SDW + row] = pi;
                    }
        }
        __syncthreads();
    }
    // P = Minv

    // ---- x_0 = dB = dt * Minv * b -> Xf row 0 (8 lanes per row) ----
    {
        int n = t >> 3, part = t & 7;
        float ar = 0.f, ai = 0.f;
#pragma unroll
        for (int qq = 0; qq < 8; ++qq) {
            int k = part + 8*qq;
            float mr = unpack2(XRr[n*SDW + k]), mi = unpack2(XRi[n*SDW + k]);
            ar += mr*bvr[k] - mi*bvi[k];
            ai += mr*bvi[k] + mi*bvr[k];
        }
#pragma unroll
        for (int off = 4; off; off >>= 1) { ar += __shfl_xor(ar, off); ai += __shfl_xor(ai, off); }
        if (part == 0) { Xfr[n] = dt*ar; Xfi[n] = dt*ai; }
    }
    __syncthreads();   // Minv reads done before transform

    // ---- P = dA = 2*Minv - I (in place, both views) ----
#pragma unroll
    for (int e = 0; e < 8; ++e) {
        int idx = t + e*NTH;
        int i = idx >> 6, j = idx & 63;
        float vr = 2.0f*unpack2(XRr[i*SDW + j]) - (i == j ? 1.0f : 0.0f);
        float vi = 2.0f*unpack2(XRi[i*SDW + j]);
        unsigned pr = pack2(vr), pi = pack2(vi);
        XRr[i*SDW + j] = pr; XRi[i*SDW + j] = pi;
        XTr[j*SDW + i] = pr; XTi[j*SDW + i] = pi;
    }
    __syncthreads();

    // ---- ladder s = 1..11: concurrent {squaring on waves 0-3} +
    //      {doubling pre-work on waves 4-5} + {K-overlap on 6-7 at s=11} ----
    // s<=6:  X-round C=2^(s-1): Xf[C+r] = Xf[r] . P^T   (Bt array = XR)
    // s>=7:  G-round C=2^(s-7): Gf[C+r] = Gf[r] . P     (Bt array = XT)
    // garbage rows (from stale A rows >= C) land in rows >= 2C, always
    // overwritten by a later round before any real use.
#pragma unroll 1
    for (int s = 1; s <= 11; ++s) {
        const bool dosq = (s <= 10);
        float4_t sR[2][2], sI[2][2];
        sR[0][0]=z4; sR[0][1]=z4; sR[1][0]=z4; sR[1][1]=z4;
        sI[0][0]=z4; sI[0][1]=z4; sI[1][0]=z4; sI[1][1]=z4;
        if (wv < 4 && dosq)
            cmm_block<2, true, true, true>(XRr, XRi, XTr, XTi,
                                           (wv>>1)*32, (wv&1)*32, fm, fq, sR, sI);
        float4_t p1R[1][2], p1I[1][2];
        p1R[0][0]=z4; p1R[0][1]=z4; p1I[0][0]=z4; p1I[0][1]=z4;
        float4_t p2R[2][2], p2I[2][2];
        p2R[0][0]=z4; p2R[0][1]=z4; p2R[1][0]=z4; p2R[1][1]=z4;
        p2I[0][0]=z4; p2I[0][1]=z4; p2I[1][0]=z4; p2I[1][1]=z4;
        int C;
        if (s <= 6) {
            C = 1 << (s-1);
            if (wv == 4 || wv == 5) {
                if (s == 6)
                    cmm_block<2, false, true, true>(Xfr, Xfi, XRr, XRi,
                                                    0, (wv-4)*32, fm, fq, p2R, p2I);
                else
                    cmm_block<1, false, true, true>(Xfr, Xfi, XRr, XRi,
                                                    0, (wv-4)*32, fm, fq, p1R, p1I);
            }
        } else {
            C = 1 << (s-7);
            if (wv == 4 || wv == 5)
                cmm_block<1, false, true, true>(Grf, Gif, XTr, XTi,
                                                0, (wv-4)*32, fm, fq, p1R, p1I);
            if (s == 11 && (wv == 6 || wv == 7))   // K[j<16][i] overlapped
                cmm_block<1, false, false, false>(Grf, Gif, Xfr, Xfi,
                                                  0, (wv-6)*32, fm, fq, p1R, p1I);
        }
        // pre-work writes (target rows read by no one this interval)
        if (wv == 4 || wv == 5) {
            const int cb = (wv-4)*32;
            if (s == 6) {
#pragma unroll
                for (int g = 0; g < 2; ++g)
#pragma unroll
                    for (int bg = 0; bg < 2; ++bg)
#pragma unroll
                        for (int r = 0; r < 4; ++r) {
                            int row = 32 + g*16 + fq*4 + r;
                            int col = cb + bg*16 + fm;
                            Xfr[row*SDW + col] = p2R[g][bg][r];
                            Xfi[row*SDW + col] = p2I[g][bg][r];
                        }
            } else if (s <= 5) {
#pragma unroll
                for (int bg = 0; bg < 2; ++bg)
#pragma unroll
                    for (int r = 0; r < 4; ++r) {
                        int row = C + fq*4 + r;
                        int col = cb + bg*16 + fm;
                        Xfr[row*SDW + col] = p1R[0][bg][r];
                        Xfi[row*SDW + col] = p1I[0][bg][r];
                    }
            } else {
#pragma unroll
                for (int bg = 0; bg < 2; ++bg)
#pragma unroll
                    for (int r = 0; r < 4; ++r) {
                        int row = C + fq*4 + r;
                        int col = cb + bg*16 + fm;
                        Grf[row*SDW + col] = p1R[0][bg][r];
                        Gif[row*SDW + col] = p1I[0][bg][r];
                    }
            }
        }
        if (s == 11 && (wv == 6 || wv == 7)) {
#pragma unroll
            for (int bg = 0; bg < 2; ++bg)
#pragma unroll
                for (int r = 0; r < 4; ++r)
                    Kof[(fq*4 + r)*65 + (wv-6)*32 + bg*16 + fm] = p1R[0][bg][r];
        }
        __syncthreads();   // all P reads complete
        if (wv < 4 && dosq) {
#pragma unroll
            for (int g = 0; g < 2; ++g)
#pragma unroll
                for (int bg = 0; bg < 2; ++bg)
#pragma unroll
                    for (int r = 0; r < 4; ++r) {
                        int row = (wv>>1)*32 + g*16 + fq*4 + r;
                        int col = (wv&1)*32 + bg*16 + fm;
                        unsigned pr = pack2(sR[g][bg][r]), pi = pack2(sI[g][bg][r]);
                        XRr[row*SDW + col] = pr; XRi[row*SDW + col] = pi;
                        XTr[col*SDW + row] = pr; XTi[col*SDW + row] = pi;
                    }
        }
        __syncthreads();
    }
    // Xf rows 0..63 = x_i ; Gf rows 0..31 = g_j ; Kof rows 0..15 done

    // ---- K rows 16..31 (waves 0,1) ----
    if (wv < 2) {
        float4_t kR[1][2], kI[1][2];
        kR[0][0]=z4; kR[0][1]=z4; kI[0][0]=z4; kI[0][1]=z4;
        cmm_block<1, false, false, false>(Grf, Gif, Xfr, Xfi, 16, wv*32, fm, fq, kR, kI);
#pragma unroll
        for (int bg = 0; bg < 2; ++bg)
#pragma unroll
            for (int r = 0; r < 4; ++r)
                Kof[(16 + fq*4 + r)*65 + wv*32 + bg*16 + fm] = kR[0][bg][r];
    }
    __syncthreads();

    // ---- coalesced store: 2048 floats as 512 float4 ----
    {
        int row = t >> 4, col = (t & 15) * 4;
        const float4_t* src = (const float4_t*)(Kof + row*65 + col);
        float4_t v = *src;
        ((float4*)(outp + (size_t)h * LSEQ))[t] = make_float4(v[0], v[1], v[2], v[3]);
    }
}

extern "C" void kernel_launch(void* const* d_in, const int* in_sizes, int n_in,
                              void* d_out, int out_size, void* d_ws, size_t ws_size,
                              hipStream_t stream) {
    const float* A  = (const float*)d_in[0];
    const float* B  = (const float*)d_in[1];
    const float* C  = (const float*)d_in[2];
    const float* ld = (const float*)d_in[3];
    float* out = (float*)d_out;
    ssm_kernel<<<dim3(NH), dim3(NTH), 0, stream>>>(A, B, C, ld, out);
}

// Round 9
// 97.185 us; speedup vs baseline: 1.0869x; 1.0869x over previous
//
#include <hip/hip_runtime.h>
#include <math.h>

// Problem constants (fixed by reference: H=256, N=64, CH=1, L=2048)
#define NH   256
#define NN   64
#define LSEQ 2048
#define SDW  68      // dword row stride: 68 mod 32 = 4 -> b128 phases tile 32 banks x2
#define NTH  1024

typedef __attribute__((ext_vector_type(8))) short short8;     // 8 bf16 (MFMA A/B frag)
typedef __attribute__((ext_vector_type(4))) float float4_t;   // MFMA C/D frag

#define MFMA(a,b,c) __builtin_amdgcn_mfma_f32_16x16x32_bf16((a),(b),(c),0,0,0)
#define PERM_HI 0x07060302u   // [a.hi16 | b.hi16]
#define PERM_LO 0x05040100u   // [a.lo16 | b.lo16]

// packed element: dword = [bf16hi | bf16lo], value = hi + lo (16-bit mantissa)
static __device__ __forceinline__ unsigned pack2(float v) {
    unsigned hv = __float_as_uint(v) & 0xffff0000u;
    float lo = v - __uint_as_float(hv);
    return __builtin_amdgcn_perm(hv, __float_as_uint(lo), PERM_HI);
}
static __device__ __forceinline__ float unpack2(unsigned w) {
    return __uint_as_float(w & 0xffff0000u) + __uint_as_float(w << 16);
}

static __device__ __forceinline__ void frag_vals(const unsigned* e, short8& hi, short8& lo) {
    unsigned lb[8];
#pragma unroll
    for (int m = 0; m < 8; ++m) {
        unsigned hv = e[m] & 0xffff0000u;
        lb[m] = __float_as_uint(__uint_as_float(e[m]) - __uint_as_float(hv));
    }
    union { short8 s; unsigned u[4]; } H, L;
#pragma unroll
    for (int m = 0; m < 4; ++m) {
        H.u[m] = __builtin_amdgcn_perm(e[2*m+1],  e[2*m],  PERM_HI);
        L.u[m] = __builtin_amdgcn_perm(lb[2*m+1], lb[2*m], PERM_HI);
    }
    hi = H.s; lo = L.s;
}
static __device__ __forceinline__ void frag_f32(const float* p, short8& hi, short8& lo) {
    const uint4* q = (const uint4*)p;
    uint4 d0 = q[0], d1 = q[1];
    unsigned e[8] = {d0.x, d0.y, d0.z, d0.w, d1.x, d1.y, d1.z, d1.w};
    frag_vals(e, hi, lo);
}
static __device__ __forceinline__ void frag_packed(const unsigned* p, short8& hi, short8& lo) {
    const uint4* q = (const uint4*)p;
    uint4 d0 = q[0], d1 = q[1];
    unsigned e[8] = {d0.x, d0.y, d0.z, d0.w, d1.x, d1.y, d1.z, d1.w};
    union { short8 s; unsigned u[4]; } H, L;
#pragma unroll
    for (int m = 0; m < 4; ++m) {
        H.u[m] = __builtin_amdgcn_perm(e[2*m+1], e[2*m], PERM_HI);
        L.u[m] = __builtin_amdgcn_perm(e[2*m+1], e[2*m], PERM_LO);
    }
    hi = H.s; lo = L.s;
}
static __device__ __forceinline__ short8 neg8(short8 v) {
    union { short8 s; int i[4]; } u; u.s = v;
#pragma unroll
    for (int m = 0; m < 4; ++m) u.i[m] ^= 0x80008000;
    return u.s;
}

// One 16x16 tile of complex P = A*B, K=64. A read as rows [arow*SDW+k..];
// B read as rows of the B-TRANSPOSE array [bcol*SDW+k..] (both b128-clean).
template<bool AP, bool BP, bool IMAG>
static __device__ __forceinline__ void cmm_tile(
    const void* Ar_, const void* Ai_, const void* Br_, const void* Bi_,
    int arow, int bcol, int fq, float4_t& accR, float4_t& accI)
{
#pragma unroll
    for (int ks = 0; ks < 2; ++ks) {
        const int k0 = ks*32 + fq*8;
        short8 Arh, Arl, Aih, Ail, Brh, Brl, Bih, Bil;
        if (AP) {
            frag_packed((const unsigned*)Ar_ + arow*SDW + k0, Arh, Arl);
            frag_packed((const unsigned*)Ai_ + arow*SDW + k0, Aih, Ail);
        } else {
            frag_f32((const float*)Ar_ + arow*SDW + k0, Arh, Arl);
            frag_f32((const float*)Ai_ + arow*SDW + k0, Aih, Ail);
        }
        if (BP) {
            frag_packed((const unsigned*)Br_ + bcol*SDW + k0, Brh, Brl);
            frag_packed((const unsigned*)Bi_ + bcol*SDW + k0, Bih, Bil);
        } else {
            frag_f32((const float*)Br_ + bcol*SDW + k0, Brh, Brl);
            frag_f32((const float*)Bi_ + bcol*SDW + k0, Bih, Bil);
        }
        short8 nAih = neg8(Aih), nAil = neg8(Ail);
        accR = MFMA(Arh, Brh, accR); accR = MFMA(Arh, Brl, accR); accR = MFMA(Arl, Brh, accR);
        accR = MFMA(nAih, Bih, accR); accR = MFMA(nAih, Bil, accR); accR = MFMA(nAil, Bih, accR);
        if (IMAG) {
            accI = MFMA(Arh, Bih, accI); accI = MFMA(Arh, Bil, accI); accI = MFMA(Arl, Bih, accI);
            accI = MFMA(Aih, Brh, accI); accI = MFMA(Aih, Brl, accI); accI = MFMA(Ail, Brh, accI);
        }
    }
}

// k[h, 64j+i] = Re( g_j . x_i ),  g_j = c^T (dA^64)^j,  x_i = dA^i dB
// Minv via ONE CUBIC Newton step from X1 = 2I - Ab = I + (dt/2)A:
//   Y = Ab*X1 ; V = X1*Y ; Minv ~= X2 = 3*X1 - 3*V + V*Y   (residual E^6, E=(dt/2)A)
// Ladder: 9 squarings to dA^512; X-rounds C=1..32; G-rounds C=1,2,4 ride the
// ladder, then three chained C=8 G-steps with dA^512 build rows 8..31.
__global__ __launch_bounds__(NTH, 4) void ssm_kernel(
    const float* __restrict__ Ag,
    const float* __restrict__ Bg,
    const float* __restrict__ Cg,
    const float* __restrict__ LogDt,
    float* __restrict__ outp)
{
    __shared__ __align__(16) unsigned char lds[130688];
    unsigned* XRr = (unsigned*)(lds +      0);   // packed P row-major (re)
    unsigned* XRi = (unsigned*)(lds +  17408);   // packed P row-major (im)
    unsigned* XTr = (unsigned*)(lds +  34816);   // packed P^T (re)
    unsigned* XTi = (unsigned*)(lds +  52224);   // packed P^T (im)
    float*    Xfr = (float*)(lds +  69632);      // fp32 Xf[v][q] = x_v[q] ; aliases Yt
    float*    Xfi = (float*)(lds +  87040);
    unsigned* U0u = (unsigned*)Xfr;              // Newton Y^T packed (dead before Xf live)
    unsigned* U1u = (unsigned*)Xfi;
    float*    Grf = (float*)(lds + 104448);      // fp32 G[j][q] = g_j[q], 32 rows, stride SDW
    float*    Gif = (float*)(lds + 113152);
    float*    Kof = (float*)(lds + 121856);      // output stage 32 x 65
    float*    bvr = (float*)(lds + 130176);
    float*    bvi = (float*)(lds + 130432);

    const int t    = threadIdx.x;
    const int lane = t & 63;
    const int wv   = t >> 6;                 // 0..15
    const int ti   = wv >> 2, tj = wv & 3;
    const int fm   = lane & 15, fq = lane >> 4;
    const int h    = blockIdx.x;

    const float dt  = expf(LogDt[h]);
    const float hdt = 0.5f * dt;

    const float2* A2 = (const float2*)(Ag + (size_t)h * NN * NN * 2);
    const float4_t z4 = {0.f, 0.f, 0.f, 0.f};

    // ---- seed P = X1 = I + (dt/2)A packed (both views); load b, c ----
#pragma unroll
    for (int e = 0; e < 4; ++e) {
        int idx = t + e*NTH;
        int i = idx >> 6, j = idx & 63;
        float2 a = A2[idx];
        unsigned pr = pack2((i == j ? 1.0f : 0.0f) + hdt * a.x);
        unsigned pi = pack2(hdt * a.y);
        XRr[i*SDW + j] = pr; XRi[i*SDW + j] = pi;
        XTr[j*SDW + i] = pr; XTi[j*SDW + i] = pi;
    }
    if (t < NN) {
        float2 bv = ((const float2*)Bg)[h*NN + t];
        float2 cv = ((const float2*)Cg)[h*NN + t];
        bvr[t] = bv.x; bvi[t] = bv.y;
        Grf[t] = cv.x; Gif[t] = cv.y;   // g_0 = c
    }
    __syncthreads();

    const int arow = ti*16 + fm;
    const int bcol = tj*16 + fm;

    // ---- m1: Y = Ab*X1 (Ab from global, Bt = XT); write Y^T -> U (b64) ----
    {
        float4_t aR = z4, aI = z4;
#pragma unroll
        for (int ks = 0; ks < 2; ++ks) {
            const int k0 = ks*32 + fq*8;
            unsigned vr[8], vi[8];
#pragma unroll
            for (int j = 0; j < 8; ++j) {
                float2 a = A2[arow*NN + k0 + j];
                vr[j] = __float_as_uint((arow == k0 + j ? 1.0f : 0.0f) - hdt * a.x);
                vi[j] = __float_as_uint(-hdt * a.y);
            }
            short8 Arh, Arl, Aih, Ail, Brh, Brl, Bih, Bil;
            frag_vals(vr, Arh, Arl);
            frag_vals(vi, Aih, Ail);
            frag_packed(XTr + bcol*SDW + k0, Brh, Brl);
            frag_packed(XTi + bcol*SDW + k0, Bih, Bil);
            short8 nAih = neg8(Aih), nAil = neg8(Ail);
            aR = MFMA(Arh, Brh, aR); aR = MFMA(Arh, Brl, aR); aR = MFMA(Arl, Brh, aR);
            aR = MFMA(nAih, Bih, aR); aR = MFMA(nAih, Bil, aR); aR = MFMA(nAil, Bih, aR);
            aI = MFMA(Arh, Bih, aI); aI = MFMA(Arh, Bil, aI); aI = MFMA(Arl, Bih, aI);
            aI = MFMA(Aih, Brh, aI); aI = MFMA(Aih, Brl, aI); aI = MFMA(Ail, Brh, aI);
        }
#pragma unroll
        for (int rp = 0; rp < 2; ++rp) {   // Yt contiguous rows -> b64
            int row0 = ti*16 + fq*4 + rp*2;
            uint2 wr; wr.x = pack2(aR[rp*2]); wr.y = pack2(aR[rp*2+1]);
            uint2 wi; wi.x = pack2(aI[rp*2]); wi.y = pack2(aI[rp*2+1]);
            *(uint2*)(U0u + bcol*SDW + row0) = wr;
            *(uint2*)(U1u + bcol*SDW + row0) = wi;
        }
    }
    __syncthreads();

    // ---- m2: V = X1*Y (A = XR, Bt = U); overwrite XR with V (row-major only) ----
    {
        float4_t aR = z4, aI = z4;
        cmm_tile<true, true, true>(XRr, XRi, U0u, U1u, arow, bcol, fq, aR, aI);
        __syncthreads();   // all X1/Y reads done
#pragma unroll
        for (int r = 0; r < 4; ++r) {
            int row = ti*16 + fq*4 + r;
            XRr[row*SDW + bcol] = pack2(aR[r]);
            XRi[row*SDW + bcol] = pack2(aI[r]);
        }
    }
    __syncthreads();

    // ---- m3: X2 = 3*X1 - 3*V + V*Y (A = XR(V), Bt = U(Yt)); write both views ----
    {
        float4_t aR = z4, aI = z4;
        cmm_tile<true, true, true>(XRr, XRi, U0u, U1u, arow, bcol, fq, aR, aI);
        float o_r[4], o_i[4];
#pragma unroll
        for (int r = 0; r < 4; ++r) {      // pre-barrier elementwise reads
            int row = ti*16 + fq*4 + r;
            float2 a = A2[row*NN + bcol];
            float x1r = (row == bcol ? 1.0f : 0.0f) + hdt * a.x;
            float x1i = hdt * a.y;
            float vvr = unpack2(XRr[row*SDW + bcol]);
            float vvi = unpack2(XRi[row*SDW + bcol]);
            o_r[r] = 3.0f*x1r - 3.0f*vvr + aR[r];
            o_i[r] = 3.0f*x1i - 3.0f*vvi + aI[r];
        }
        __syncthreads();   // all V/Y reads done
        unsigned pr[4], pi[4];
#pragma unroll
        for (int r = 0; r < 4; ++r) {
            int row = ti*16 + fq*4 + r;
            pr[r] = pack2(o_r[r]); pi[r] = pack2(o_i[r]);
            XRr[row*SDW + bcol] = pr[r]; XRi[row*SDW + bcol] = pi[r];
        }
#pragma unroll
        for (int rp = 0; rp < 2; ++rp) {
            int row0 = ti*16 + fq*4 + rp*2;
            uint2 wr; wr.x = pr[rp*2]; wr.y = pr[rp*2+1];
            uint2 wi; wi.x = pi[rp*2]; wi.y = pi[rp*2+1];
            *(uint2*)(XTr + bcol*SDW + row0) = wr;
            *(uint2*)(XTi + bcol*SDW + row0) = wi;
        }
    }
    __syncthreads();
    // P = Minv

    // ---- x_0 = dB = dt * Minv * b -> Xf row 0 ----
    {
        int n = t >> 4, part = t & 15;
        float ar = 0.f, ai = 0.f;
#pragma unroll
        for (int qq = 0; qq < 4; ++qq) {
            int k = part + 16*qq;
            float mr = unpack2(XRr[n*SDW + k]), mi = unpack2(XRi[n*SDW + k]);
            ar += mr*bvr[k] - mi*bvi[k];
            ai += mr*bvi[k] + mi*bvr[k];
        }
#pragma unroll
        for (int off = 8; off; off >>= 1) { ar += __shfl_xor(ar, off); ai += __shfl_xor(ai, off); }
        if (part == 0) { Xfr[n] = dt*ar; Xfi[n] = dt*ai; }
    }
    __syncthreads();

    // ---- P = dA = 2*Minv - I (in place, both views) ----
#pragma unroll
    for (int e = 0; e < 4; ++e) {
        int idx = t + e*NTH;
        int i = idx >> 6, j = idx & 63;
        float vr = 2.0f*unpack2(XRr[i*SDW + j]) - (i == j ? 1.0f : 0.0f);
        float vi = 2.0f*unpack2(XRi[i*SDW + j]);
        unsigned pr = pack2(vr), pi = pack2(vi);
        XRr[i*SDW + j] = pr; XRi[i*SDW + j] = pi;
        XTr[j*SDW + i] = pr; XTi[j*SDW + i] = pi;
    }
    __syncthreads();

    // ---- ladder s = 1..9: pre-work rides (P = dA^(2^(s-1))) + squaring ----
    // s<=6: X-round C=2^(s-1): Xf[C+r] = Xf[r].P^T (Bt = XR)
    // s>=7: G-round C=2^(s-7): Gf[C+r] = Gf[r].P   (Bt = XT)
    // garbage rows propagate only to rows >= 2C, overwritten before use.
#pragma unroll 1
    for (int s = 1; s <= 9; ++s) {
        if (s <= 6) {
            const int C = 1 << (s-1);
            const int nT = (s == 6) ? 8 : 4;
            if (wv < nT) {
                const int rt = wv >> 2, ct = wv & 3;
                float4_t aR = z4, aI = z4;
                cmm_tile<false, true, true>(Xfr, Xfi, XRr, XRi, rt*16 + fm, ct*16 + fm, fq, aR, aI);
#pragma unroll
                for (int r = 0; r < 4; ++r) {
                    int row = rt*16 + fq*4 + r;
                    Xfr[(C+row)*SDW + ct*16 + fm] = aR[r];
                    Xfi[(C+row)*SDW + ct*16 + fm] = aI[r];
                }
            }
        } else {
            const int C = 1 << (s-7);     // 1,2,4
            if (wv < 4) {
                float4_t aR = z4, aI = z4;
                cmm_tile<false, true, true>(Grf, Gif, XTr, XTi, fm, wv*16 + fm, fq, aR, aI);
#pragma unroll
                for (int r = 0; r < 4; ++r) {
                    int row = fq*4 + r;
                    Grf[(C+row)*SDW + wv*16 + fm] = aR[r];
                    Gif[(C+row)*SDW + wv*16 + fm] = aI[r];
                }
            }
        }
        // squaring (all 16 waves): P <- P*P
        float4_t sR = z4, sI = z4;
        cmm_tile<true, true, true>(XRr, XRi, XTr, XTi, arow, bcol, fq, sR, sI);
        __syncthreads();
        unsigned pr[4], pi[4];
#pragma unroll
        for (int r = 0; r < 4; ++r) {
            int row = ti*16 + fq*4 + r;
            pr[r] = pack2(sR[r]); pi[r] = pack2(sI[r]);
            XRr[row*SDW + bcol] = pr[r]; XRi[row*SDW + bcol] = pi[r];
        }
#pragma unroll
        for (int rp = 0; rp < 2; ++rp) {
            int row0 = ti*16 + fq*4 + rp*2;
            uint2 wr; wr.x = pr[rp*2]; wr.y = pr[rp*2+1];
            uint2 wi; wi.x = pi[rp*2]; wi.y = pi[rp*2+1];
            *(uint2*)(XTr + bcol*SDW + row0) = wr;
            *(uint2*)(XTi + bcol*SDW + row0) = wi;
        }
        __syncthreads();
    }
    // P = dA^512 ; Xf rows 0..63 = x_i ; Gf rows 0..7 = g_0..g_7

    // ---- tail t = 0..3: chained C=8 G-steps with dA^512 + masked K tiles ----
    // t: G rows [8+ab, 8+ab+16) <- A rows [ab, ab+16) (ab = 0,8,16; t<3)
    //    K rows [jb, jb+8)      <- G rows [jb, jb+8)   (jb = 8t)
#pragma unroll 1
    for (int tt = 0; tt < 4; ++tt) {
        if (tt < 3 && wv < 4) {            // G-step, 4 waves
            const int ab = tt * 8;
            float4_t aR = z4, aI = z4;
            cmm_tile<false, true, true>(Grf, Gif, XTr, XTi, ab + fm, wv*16 + fm, fq, aR, aI);
#pragma unroll
            for (int r = 0; r < 4; ++r) {
                int orow = 8 + ab + fq*4 + r;
                if (orow < 32) {
                    Grf[orow*SDW + wv*16 + fm] = aR[r];
                    Gif[orow*SDW + wv*16 + fm] = aI[r];
                }
            }
        }
        if (wv >= 4 && wv < 8) {           // K tiles, 4 waves, rows jb..jb+7
            const int jb = tt * 8;
            float4_t aR = z4, aI = z4;
            cmm_tile<false, false, false>(Grf, Gif, Xfr, Xfi, jb + fm, (wv-4)*16 + fm, fq, aR, aI);
            if (fq < 2) {
#pragma unroll
                for (int r = 0; r < 4; ++r)
                    Kof[(jb + fq*4 + r)*65 + (wv-4)*16 + fm] = aR[r];
            }
        }
        __syncthreads();
    }

    // ---- coalesced store: 2048 floats as 1024 float2 ----
    {
        int row = t >> 5, col = (t & 31) * 2;
        float2 v = { Kof[row*65 + col], Kof[row*65 + col + 1] };
        ((float2*)(outp + (size_t)h * LSEQ))[t] = v;
    }
}

extern "C" void kernel_launch(void* const* d_in, const int* in_sizes, int n_in,
                              void* d_out, int out_size, void* d_ws, size_t ws_size,
                              hipStream_t stream) {
    const float* A  = (const float*)d_in[0];
    const float* B  = (const float*)d_in[1];
    const float* C  = (const float*)d_in[2];
    const float* ld = (const float*)d_in[3];
    float* out = (float*)d_out;
    ssm_kernel<<<dim3(NH), dim3(NTH), 0, stream>>>(A, B, C, ld, out);
}